// Round 6
// baseline (508.547 us; speedup 1.0000x reference)
//
#include <hip/hip_runtime.h>

// Problem constants (from reference setup_inputs)
#define BB 2
#define NN 4096
#define DD 512
#define EE 16
#define HH 2048
#define CAP 1024            // capacity = int((4096*2)*2.0/16) = 1024
#define NTOK (BB*NN)        // 8192
#define MM (BB*CAP)         // 2048 = per-expert logical M

typedef unsigned short ushort_t;
typedef __attribute__((ext_vector_type(8))) short bf16x8;   // 8 bf16 = 4 VGPRs
typedef __attribute__((ext_vector_type(4))) float floatx4;  // MFMA accumulator

// round-to-nearest-even f32 -> bf16 bit pattern
__device__ __forceinline__ ushort_t f2bf(float f) {
    union { float f; unsigned u; } v; v.f = f;
    unsigned r = v.u + 0x7fffu + ((v.u >> 16) & 1u);
    return (ushort_t)(r >> 16);
}

// async global->LDS, 16B per lane (global_load_lds_dwordx4).
__device__ __forceinline__ void cp16(const void* g, void* l) {
    __builtin_amdgcn_global_load_lds(
        (const __attribute__((address_space(1))) void*)g,
        (__attribute__((address_space(3))) void*)l, 16, 0, 0);
}

// ---------------------------------------------------------------------------
// Kernel 1: gating (f32-exact selection) + fused bf16 conversion of x.
// ---------------------------------------------------------------------------
__launch_bounds__(256)
__global__ void gating_kernel(const float* __restrict__ x,
                              const float* __restrict__ wg,
                              int* __restrict__ e1, int* __restrict__ e2,
                              float* __restrict__ g1, float* __restrict__ g2,
                              ushort_t* __restrict__ xbf) {
    int wave = threadIdx.x >> 6;
    int lane = threadIdx.x & 63;
    int t = blockIdx.x * 4 + wave;
    const float* xp = x + (size_t)t * DD;

    float4 xa = ((const float4*)xp)[lane * 2];
    float4 xb = ((const float4*)xp)[lane * 2 + 1];
    float xs[8] = {xa.x, xa.y, xa.z, xa.w, xb.x, xb.y, xb.z, xb.w};

    ushort4 h0, h1;
    h0.x = f2bf(xs[0]); h0.y = f2bf(xs[1]); h0.z = f2bf(xs[2]); h0.w = f2bf(xs[3]);
    h1.x = f2bf(xs[4]); h1.y = f2bf(xs[5]); h1.z = f2bf(xs[6]); h1.w = f2bf(xs[7]);
    ushort4* xo = (ushort4*)(xbf + (size_t)t * DD);
    xo[lane * 2] = h0; xo[lane * 2 + 1] = h1;

    float acc[EE];
#pragma unroll
    for (int e = 0; e < EE; e++) acc[e] = 0.f;
    int d0 = lane * 8;
#pragma unroll
    for (int j = 0; j < 8; j++) {
        const float* wrow = wg + (d0 + j) * EE;
#pragma unroll
        for (int e = 0; e < EE; e++) acc[e] = fmaf(xs[j], wrow[e], acc[e]);
    }
#pragma unroll
    for (int off = 32; off > 0; off >>= 1) {
#pragma unroll
        for (int e = 0; e < EE; e++) acc[e] += __shfl_xor(acc[e], off, 64);
    }
    if (lane == 0) {
        float m = acc[0];
#pragma unroll
        for (int e = 1; e < EE; e++) m = fmaxf(m, acc[e]);
        float p[EE]; float s = 0.f;
#pragma unroll
        for (int e = 0; e < EE; e++) { p[e] = __expf(acc[e] - m); s += p[e]; }
        float inv = 1.f / s;
#pragma unroll
        for (int e = 0; e < EE; e++) p[e] *= inv;
        int i1 = 0; float v1 = p[0];
#pragma unroll
        for (int e = 1; e < EE; e++) if (p[e] > v1) { v1 = p[e]; i1 = e; }
        int i2 = (i1 == 0) ? 1 : 0; float v2 = p[i2];
#pragma unroll
        for (int e = 0; e < EE; e++)
            if (e != i1 && p[e] > v2) { v2 = p[e]; i2 = e; }
        float denom = v1 + v2 + 1e-9f;
        e1[t] = i1; e2[t] = i2;
        g1[t] = v1 / denom; g2[t] = v2 / denom;
    }
}

// ---------------------------------------------------------------------------
// Kernel 2: per-(b,e) exclusive scan -> slot assignment with capacity drop.
// Writes s2t (token or -1 for ALL CAP slots), s2g, used[e][b].
// ---------------------------------------------------------------------------
__launch_bounds__(256)
__global__ void scan_kernel(const int* __restrict__ e1, const int* __restrict__ e2,
                            const float* __restrict__ g1, const float* __restrict__ g2,
                            int* __restrict__ s2t, float* __restrict__ s2g,
                            int* __restrict__ used) {
    int b = blockIdx.x / EE;
    int e = blockIdx.x % EE;
    int tid = threadIdx.x;
    const int base = b * NN;
    int n0 = tid * 16;

    unsigned m1 = 0, m2 = 0;
    int c1 = 0, c2 = 0;
#pragma unroll
    for (int j = 0; j < 16; j++) {
        int n = n0 + j;
        if (e1[base + n] == e) { m1 |= 1u << j; c1++; }
        if (e2[base + n] == e) { m2 |= 1u << j; c2++; }
    }
    __shared__ int s1[256], s2[256];
    __shared__ int s_used;
    s1[tid] = c1; s2[tid] = c2;
    __syncthreads();
    for (int off = 1; off < 256; off <<= 1) {
        int a1 = (tid >= off) ? s1[tid - off] : 0;
        int a2 = (tid >= off) ? s2[tid - off] : 0;
        __syncthreads();
        s1[tid] += a1; s2[tid] += a2;
        __syncthreads();
    }
    int total1 = s1[255];
    int total2 = s2[255];
    int kept1 = min(total1, CAP);
    int ex1 = s1[tid] - c1;
    int ex2 = s2[tid] - c2 + kept1;
    const int sbase = (e * BB + b) * CAP;
#pragma unroll
    for (int j = 0; j < 16; j++) {
        int n = n0 + j;
        if (m1 & (1u << j)) {
            if (ex1 < CAP) { s2t[sbase + ex1] = base + n; s2g[sbase + ex1] = g1[base + n]; }
            ex1++;
        }
        if (m2 & (1u << j)) {
            if (ex2 < CAP) { s2t[sbase + ex2] = base + n; s2g[sbase + ex2] = g2[base + n]; }
            ex2++;
        }
    }
    if (tid == 255) {
        int kept2 = min(total2, max(0, CAP - kept1));
        int u = kept1 + kept2;
        used[e * BB + b] = u;
        s_used = u;
    }
    __syncthreads();
    for (int i = s_used + tid; i < CAP; i += 256) s2t[sbase + i] = -1;
}

// ---------------------------------------------------------------------------
// Kernel 3: build XCD-pinned job lists for the fused FFN. Expert e -> XCD e&7.
// Per (e,b): ceil(used/128) strips of 128 slots. Max 32 jobs/XCD (guaranteed:
// 2 experts x 2 b x 8 strips). job = (e<<8) | (slot0>>7).
// meta: [0..7] = count per XCD, [8 + x*32 + j] = job.
// ---------------------------------------------------------------------------
__global__ void schedule_kernel(const int* __restrict__ used, int* __restrict__ meta) {
    int x = threadIdx.x;
    if (x >= 8) return;
    int cnt = 0;
#pragma unroll
    for (int ei = 0; ei < 2; ei++) {
        int e = x + ei * 8;
        for (int b = 0; b < 2; b++) {
            int ns = (used[e * BB + b] + 127) >> 7;
            for (int s = 0; s < ns; s++)
                meta[8 + x * 32 + cnt++] = (e << 8) | ((e * BB + b) * 8 + s);
        }
    }
    meta[x] = cnt;
}

// ---------------------------------------------------------------------------
// Kernel 4: per-expert transpose + bf16: f32 [E][R][C] -> bf16 [E][C][R].
// 64x64 tiles; float2 reads, ushort2 writes (full 256B/wave write segments).
// ---------------------------------------------------------------------------
__global__ void transpose_bf16(const float* __restrict__ in,
                               ushort_t* __restrict__ outp, int R, int C) {
    __shared__ float tile[64][65];
    const float* slab = in + (size_t)blockIdx.z * R * C;
    ushort_t* oslab = outp + (size_t)blockIdx.z * R * C;
    int c0 = blockIdx.x * 64, r0 = blockIdx.y * 64;
    int tx = threadIdx.x, ty = threadIdx.y;   // (32, 8)
#pragma unroll
    for (int j = 0; j < 8; j++) {
        int r = ty + j * 8;
        float2 v = *(const float2*)&slab[(size_t)(r0 + r) * C + c0 + tx * 2];
        tile[r][tx * 2] = v.x; tile[r][tx * 2 + 1] = v.y;
    }
    __syncthreads();
#pragma unroll
    for (int j = 0; j < 8; j++) {
        int c = ty + j * 8;
        ushort2 h;
        h.x = f2bf(tile[tx * 2][c]);
        h.y = f2bf(tile[tx * 2 + 1][c]);
        *(ushort2*)&oslab[(size_t)(c0 + c) * R + r0 + tx * 2] = h;
    }
}

// ---------------------------------------------------------------------------
// Kernel 5: FUSED expert FFN. One 512-thread block per 128-row strip; the
// whole 512-wide output accumulates in registers (acc[4][8] = 128 f32/lane).
// Per h-chunk (256): G1 hid_c = relu(A @ W1[:,c]) -> LDS (bf16, XOR-swizzled
// k-major); G2 out_acc += hid_c @ W2[c,:]. hid never touches HBM. Staging via
// dbuf global_load_lds + fine vmcnt. Epilogue: gate-weighted atomicAdd.
// LDS: A dbuf 16K + W dbuf 64K + hid 64K = 144 KB (gfx950 has 160).
// ---------------------------------------------------------------------------
__launch_bounds__(512)
__global__ void fused_ffn(const ushort_t* __restrict__ xbf,
                          const ushort_t* __restrict__ w1t,
                          const ushort_t* __restrict__ w2t,
                          float* __restrict__ outp,
                          const int* __restrict__ meta,
                          const int* __restrict__ s2t,
                          const float* __restrict__ s2g) {
    int xcd = blockIdx.x;
    if ((int)blockIdx.y >= meta[xcd]) return;
    int job = meta[8 + xcd * 32 + blockIdx.y];
    int e = job >> 8;
    int slot0 = (job & 255) << 7;

    __shared__ ushort_t Ats[2][128 * 32];   // A k-slice, [m][32k]
    __shared__ ushort_t Wts[2][512 * 32];   // W k-slice, [n][32k] (G1 uses 256 rows)
    __shared__ ushort_t Hs[128 * 256];      // hid chunk, [m][256k], chunk^=(m&15)

    const int tid = threadIdx.x;
    const int lane = tid & 63;
    const int wid = tid >> 6;
    const int lm = lane & 15;
    const int quad = lane >> 4;
    const int swz = (quad ^ ((lm >> 1) & 3)) * 8;

    const int mh   = (wid & 1) << 6;    // m-offset, both phases
    const int g1_n = (wid >> 1) << 6;   // G1 n-offset in chunk (0..192)
    const int g2_n = (wid >> 1) << 7;   // G2 n-offset in out   (0..384)

    // --- per-thread staging pointers (wave-uniform LDS dst + lane-linear) ---
    int arow = tid >> 2;
    int tokA = s2t[slot0 + arow];
    const ushort_t* gA = xbf + (size_t)(tokA < 0 ? 0 : tokA) * DD
                             + ((tid & 3) ^ ((arow >> 1) & 3)) * 8;
    const ushort_t* w1b = w1t + ((size_t)e << 20);
    const ushort_t* w2b = w2t + ((size_t)e << 20);
    int r0 = tid >> 2, r1 = 128 + (tid >> 2);
    const ushort_t* gW1a = w1b + (size_t)r0 * DD + ((tid & 3) ^ ((r0 >> 1) & 3)) * 8;
    const ushort_t* gW1b = w1b + (size_t)r1 * DD + ((tid & 3) ^ ((r1 >> 1) & 3)) * 8;
    const ushort_t* gW2[4];
#pragma unroll
    for (int it = 0; it < 4; it++) {
        int r = it * 128 + (tid >> 2);
        gW2[it] = w2b + (size_t)r * HH + ((tid & 3) ^ ((r >> 1) & 3)) * 8;
    }

    floatx4 acc[4][8];
#pragma unroll
    for (int i = 0; i < 4; i++)
#pragma unroll
        for (int j = 0; j < 8; j++)
            acc[i][j] = (floatx4)(0.f);

    for (int chunk = 0; chunk < HH / 256; chunk++) {
        // ---------------- G1: hid_c = relu(A @ W1[:, chunk]) ----------------
        floatx4 acch[4][4];
#pragma unroll
        for (int i = 0; i < 4; i++)
#pragma unroll
            for (int j = 0; j < 4; j++)
                acch[i][j] = (floatx4)(0.f);
        {
            const ushort_t* p1 = gW1a + ((size_t)chunk << 17);
            const ushort_t* p2 = gW1b + ((size_t)chunk << 17);
            cp16(gA, &Ats[0][tid * 8]);
            cp16(p1, &Wts[0][tid * 8]);
            cp16(p2, &Wts[0][(512 + tid) * 8]);
            for (int kk = 0; kk < 16; kk++) {
                int cur = kk & 1;
                if (kk < 15) {
                    int nx = cur ^ 1, ko = (kk + 1) * 32;
                    cp16(gA + ko, &Ats[nx][tid * 8]);
                    cp16(p1 + ko, &Wts[nx][tid * 8]);
                    cp16(p2 + ko, &Wts[nx][(512 + tid) * 8]);
                    asm volatile("s_waitcnt vmcnt(3)\ns_barrier" ::: "memory");
                } else {
                    asm volatile("s_waitcnt vmcnt(0)\ns_barrier" ::: "memory");
                }
                bf16x8 af[4];
#pragma unroll
                for (int mt = 0; mt < 4; mt++)
                    af[mt] = *(const bf16x8*)&Ats[cur][(mh + mt * 16 + lm) * 32 + swz];
#pragma unroll
                for (int nt = 0; nt < 4; nt++) {
                    bf16x8 bf = *(const bf16x8*)&Wts[cur][(g1_n + nt * 16 + lm) * 32 + swz];
#pragma unroll
                    for (int mt = 0; mt < 4; mt++)
                        acch[mt][nt] = __builtin_amdgcn_mfma_f32_16x16x32_bf16(
                            af[mt], bf, acch[mt][nt], 0, 0, 0);
                }
                asm volatile("s_waitcnt lgkmcnt(0)\ns_barrier" ::: "memory");
            }
        }
        // hid -> LDS (C-layout scatter; chunk col XOR (m&15) for G2 frag reads)
#pragma unroll
        for (int mt = 0; mt < 4; mt++)
#pragma unroll
            for (int nt = 0; nt < 4; nt++)
#pragma unroll
                for (int r = 0; r < 4; r++) {
                    int row = mh + mt * 16 + quad * 4 + r;
                    int col = g1_n + nt * 16 + lm;
                    int ch = (col >> 3) ^ (row & 15);
                    Hs[row * 256 + ch * 8 + (col & 7)] =
                        f2bf(fmaxf(acch[mt][nt][r], 0.f));
                }
        asm volatile("s_waitcnt lgkmcnt(0)\ns_barrier" ::: "memory");

        // ---------------- G2: out_acc += hid_c @ W2[chunk, :] ----------------
        {
            size_t co = (size_t)chunk << 8;   // k-offset into W2t rows
            cp16(gW2[0] + co, &Wts[0][tid * 8]);
            cp16(gW2[1] + co, &Wts[0][(512 + tid) * 8]);
            cp16(gW2[2] + co, &Wts[0][(1024 + tid) * 8]);
            cp16(gW2[3] + co, &Wts[0][(1536 + tid) * 8]);
            for (int kk = 0; kk < 8; kk++) {
                int cur = kk & 1;
                if (kk < 7) {
                    int nx = cur ^ 1; size_t ko = co + (kk + 1) * 32;
                    cp16(gW2[0] + ko, &Wts[nx][tid * 8]);
                    cp16(gW2[1] + ko, &Wts[nx][(512 + tid) * 8]);
                    cp16(gW2[2] + ko, &Wts[nx][(1024 + tid) * 8]);
                    cp16(gW2[3] + ko, &Wts[nx][(1536 + tid) * 8]);
                    asm volatile("s_waitcnt vmcnt(4)\ns_barrier" ::: "memory");
                } else {
                    asm volatile("s_waitcnt vmcnt(0)\ns_barrier" ::: "memory");
                }
                bf16x8 ah[4];
#pragma unroll
                for (int mt = 0; mt < 4; mt++) {
                    int row = mh + mt * 16 + lm;
                    int ch = ((kk << 2) + quad) ^ lm;   // row&15 == lm
                    ah[mt] = *(const bf16x8*)&Hs[row * 256 + ch * 8];
                }
#pragma unroll
                for (int nt = 0; nt < 8; nt++) {
                    bf16x8 bf = *(const bf16x8*)&Wts[cur][(g2_n + nt * 16 + lm) * 32 + swz];
#pragma unroll
                    for (int mt = 0; mt < 4; mt++)
                        acc[mt][nt] = __builtin_amdgcn_mfma_f32_16x16x32_bf16(
                            ah[mt], bf, acc[mt][nt], 0, 0, 0);
                }
                asm volatile("s_waitcnt lgkmcnt(0)\ns_barrier" ::: "memory");
            }
        }
    }

    // epilogue: gate-weighted scatter-add (C/D layout col=lane&15, row=quad*4+r)
#pragma unroll
    for (int mt = 0; mt < 4; mt++)
#pragma unroll
        for (int r = 0; r < 4; r++) {
            int row = mh + mt * 16 + quad * 4 + r;
            int slot = slot0 + row;
            int tok = s2t[slot];
            if (tok < 0) continue;
            float g = s2g[slot];
#pragma unroll
            for (int nt = 0; nt < 8; nt++) {
                int col = g2_n + nt * 16 + lm;
                atomicAdd(outp + (size_t)tok * DD + col, g * acc[mt][nt][r]);
            }
        }
}

// ---------------------------------------------------------------------------
// Workspace layout (bytes), total ~72.4 MB:
//   0        e1 32768 | 32768 e2 | 65536 g1 | 98304 g2
//   131072   used (pad 1024)
//   132096   meta (264 ints, pad 4096)
//   136192   s2t  131072
//   267264   s2g  131072
//   398336   xbf  bf16 [8192][512]        =  8,388,608
//   8786944  w1t  bf16 [16][2048][512]    = 33,554,432
//   42341376 w2t  bf16 [16][512][2048]    = 33,554,432
// ---------------------------------------------------------------------------
extern "C" void kernel_launch(void* const* d_in, const int* in_sizes, int n_in,
                              void* d_out, int out_size, void* d_ws, size_t ws_size,
                              hipStream_t stream) {
    const float* x  = (const float*)d_in[0];
    const float* wg = (const float*)d_in[1];
    const float* w1 = (const float*)d_in[2];
    const float* w2 = (const float*)d_in[3];
    float* out = (float*)d_out;

    char* ws = (char*)d_ws;
    int*      e1   = (int*)(ws);
    int*      e2   = (int*)(ws + 32768);
    float*    g1   = (float*)(ws + 65536);
    float*    g2   = (float*)(ws + 98304);
    int*      used = (int*)(ws + 131072);
    int*      meta = (int*)(ws + 132096);
    int*      s2t  = (int*)(ws + 136192);
    float*    s2g  = (float*)(ws + 267264);
    ushort_t* xbf  = (ushort_t*)(ws + 398336);
    ushort_t* w1t  = (ushort_t*)(ws + 8786944);
    ushort_t* w2t  = (ushort_t*)(ws + 42341376);

    hipMemsetAsync(out, 0, (size_t)NTOK * DD * sizeof(float), stream);

    gating_kernel<<<NTOK / 4, 256, 0, stream>>>(x, wg, e1, e2, g1, g2, xbf);
    scan_kernel<<<BB * EE, 256, 0, stream>>>(e1, e2, g1, g2, s2t, s2g, used);
    schedule_kernel<<<1, 64, 0, stream>>>(used, meta);

    // w1 [e][512][2048] -> w1t [e][2048][512];  w2 [e][2048][512] -> w2t [e][512][2048]
    transpose_bf16<<<dim3(HH / 64, DD / 64, EE), dim3(32, 8), 0, stream>>>(w1, w1t, DD, HH);
    transpose_bf16<<<dim3(DD / 64, HH / 64, EE), dim3(32, 8), 0, stream>>>(w2, w2t, HH, DD);

    fused_ffn<<<dim3(8, 32), 512, 0, stream>>>(xbf, w1t, w2t, out, meta, s2t, s2g);
}